// Round 1
// baseline (2516.088 us; speedup 1.0000x reference)
//
#include <hip/hip_runtime.h>
#include <cstdint>
#include <cstddef>

#define B_ 4096
#define T_ 128
#define N_ 128
#define H_ 128
#define G4_ 512       // 4*H
#define KC_ 256       // concat K = [x|h]
#define EPS_ 1e-5f

typedef _Float16 f16x8 __attribute__((ext_vector_type(8)));
typedef float f32x4 __attribute__((ext_vector_type(4)));

__device__ __forceinline__ float sigm_(float x) { return 1.f / (1.f + __expf(-x)); }
__device__ __forceinline__ float tanh_(float x) {
  float ax = fabsf(x);
  float e = __expf(-2.f * ax);
  float t = (1.f - e) / (1.f + e);
  return copysignf(t, x);
}

// ---------------- K0: pack weights to f16 [2][512][256] = [Wih | Whh], combine biases, zero stats
__global__ void k0_prep(const float* __restrict__ Wih0, const float* __restrict__ Whh0,
                        const float* __restrict__ bih0, const float* __restrict__ bhh0,
                        const float* __restrict__ Wih1, const float* __restrict__ Whh1,
                        const float* __restrict__ bih1, const float* __restrict__ bhh1,
                        _Float16* __restrict__ Wpack, float* __restrict__ bpack,
                        float* __restrict__ sumb, float* __restrict__ sqb) {
  int idx = blockIdx.x * blockDim.x + threadIdx.x;
  if (idx < 2 * G4_ * KC_) {
    int k = idx & (KC_ - 1);
    int j = (idx >> 8) & (G4_ - 1);
    int l = idx >> 17;
    const float* Wih = l ? Wih1 : Wih0;
    const float* Whh = l ? Whh1 : Whh0;
    float v = (k < N_) ? Wih[j * N_ + k] : Whh[j * N_ + (k - N_)];
    Wpack[idx] = (_Float16)v;
  }
  if (idx < 2 * G4_) {
    int j = idx & (G4_ - 1);
    bpack[idx] = (idx >> 9) ? (bih1[j] + bhh1[j]) : (bih0[j] + bhh0[j]);
  }
  if (idx < T_ * N_) { sumb[idx] = 0.f; sqb[idx] = 0.f; }
}

// ---------------- K1: score_x + softmax over n -> alpha[b][n]  (time-invariant!)
__global__ void k1_alpha(const float* __restrict__ X, const float* __restrict__ attn_w,
                         const float* __restrict__ attn_b, float* __restrict__ alpha) {
  __shared__ float wx[T_];
  __shared__ float red[4];
  int b = blockIdx.x;
  int n = threadIdx.x;  // 0..127
  wx[n] = attn_w[2 * H_ + n];
  __syncthreads();
  const float* xp = X + (size_t)b * T_ * N_ + n;
  float s = 0.f;
#pragma unroll 8
  for (int t = 0; t < T_; ++t) s = fmaf(xp[t * N_], wx[t], s);
  s += attn_b[0];
  float m = s;
#pragma unroll
  for (int off = 32; off >= 1; off >>= 1) m = fmaxf(m, __shfl_xor(m, off));
  if ((n & 63) == 0) red[n >> 6] = m;
  __syncthreads();
  m = fmaxf(red[0], red[1]);
  float e = __expf(s - m);
  float sm = e;
#pragma unroll
  for (int off = 32; off >= 1; off >>= 1) sm += __shfl_xor(sm, off);
  if ((n & 63) == 0) red[2 + (n >> 6)] = sm;
  __syncthreads();
  sm = red[2] + red[3];
  alpha[b * N_ + n] = e / sm;
}

// ---------------- K2: X_tilde = alpha*X (write output 0) + BN partial stats per (t,n)
__global__ void k2_xtilde(const float* __restrict__ X, const float* __restrict__ alpha,
                          float* __restrict__ out0, float* __restrict__ sumb,
                          float* __restrict__ sqb) {
  int t = blockIdx.x;
  int chunk = blockIdx.y;
  int n = threadIdx.x & (N_ - 1);
  int bi = threadIdx.x >> 7;  // 0/1
  float s = 0.f, q = 0.f;
  for (int it = 0; it < 128; ++it) {
    int b = (chunk << 8) + (it << 1) + bi;
    float a = alpha[b * N_ + n];
    size_t off = ((size_t)b * T_ + t) * N_ + n;
    float v = a * X[off];
    out0[off] = v;
    s += v;
    q += v * v;
  }
  __shared__ float ps[2][N_], pq[2][N_];
  ps[bi][n] = s;
  pq[bi][n] = q;
  __syncthreads();
  if (bi == 0) {
    atomicAdd(&sumb[t * N_ + n], ps[0][n] + ps[1][n]);
    atomicAdd(&sqb[t * N_ + n], pq[0][n] + pq[1][n]);
  }
}

// ---------------- K3: finalize BN -> per-(t,n) scale/shift
__global__ void k3_finalize(const float* __restrict__ sumb, const float* __restrict__ sqb,
                            const float* __restrict__ gamma, const float* __restrict__ beta,
                            float* __restrict__ scale, float* __restrict__ shift) {
  int i = blockIdx.x * blockDim.x + threadIdx.x;
  if (i >= T_ * N_) return;
  int n = i & (N_ - 1);
  float mean = sumb[i] * (1.f / B_);
  float var = sqb[i] * (1.f / B_) - mean * mean;
  float rstd = rsqrtf(var + EPS_);
  float g = gamma[n];
  scale[i] = rstd * g;
  shift[i] = beta[n] - mean * rstd * g;
}

// ---------------- K4: 2-layer LSTM recurrence. 128 blocks x 32 rows, 8 waves.
// Wave w owns gate cols [w*64, w*64+64): 4 n-tiles x 2 m-tiles, K=256 via 16x16x32 f16 MFMA.
#define NB_ 128
#define RPB_ 32

// GEMM over A (LDS, [RPB_][264] f16, K=256) with weights layer L; writes gates+bias to G.
#define GEMM_LAYER(Abuf, LOFF, BIA)                                                        \
  {                                                                                        \
    f32x4 acc[2][4] = {};                                                                  \
    _Pragma("unroll") for (int kb = 0; kb < 8; ++kb) {                                     \
      f16x8 a0 = *(const f16x8*)&Abuf[l16][(kb << 5) + (quad << 3)];                       \
      f16x8 a1 = *(const f16x8*)&Abuf[16 + l16][(kb << 5) + (quad << 3)];                  \
      _Pragma("unroll") for (int nt = 0; nt < 4; ++nt) {                                   \
        const _Float16* wp = Wpack + (size_t)((LOFF) + (w << 6) + (nt << 4) + l16) * KC_ + \
                             (kb << 5) + (quad << 3);                                      \
        f16x8 bf = *(const f16x8*)wp;                                                      \
        acc[0][nt] = __builtin_amdgcn_mfma_f32_16x16x32_f16(a0, bf, acc[0][nt], 0, 0, 0);  \
        acc[1][nt] = __builtin_amdgcn_mfma_f32_16x16x32_f16(a1, bf, acc[1][nt], 0, 0, 0);  \
      }                                                                                    \
    }                                                                                      \
    _Pragma("unroll") for (int mt = 0; mt < 2; ++mt)                                       \
        _Pragma("unroll") for (int nt = 0; nt < 4; ++nt)                                   \
            _Pragma("unroll") for (int rg = 0; rg < 4; ++rg)                               \
                G[gidx][(mt << 4) + (quad << 2) + rg][cw + (nt << 4) + l16] =              \
                    acc[mt][nt][rg] + BIA[nt];                                             \
  }

__global__ __launch_bounds__(512, 2) void k4_recur(
    const float* __restrict__ xt /* X_tilde */, const _Float16* __restrict__ Wpack,
    const float* __restrict__ bpack, const float* __restrict__ scale,
    const float* __restrict__ shift, float* __restrict__ out1) {
  __shared__ _Float16 A0[RPB_][264];  // [x_b | h0], +8 f16 pad (bank rotate)
  __shared__ _Float16 A1[RPB_][264];  // [h0n | h1]
  __shared__ float G[4][RPB_][132];   // gate exchange i/f/g/o
  const int tid = threadIdx.x;
  const int w = tid >> 6;
  const int lane = tid & 63;
  const int quad = lane >> 4;
  const int l16 = lane & 15;
  const int r_act = tid >> 4;          // 0..31
  const int c_act = (tid & 15) << 3;   // 0..120
  const int nb = blockIdx.x;
  const int gidx = w >> 1;             // gate type owned by this wave
  const int cw = (w & 1) << 6;         // col base within gate

  float bia0[4], bia1[4];
#pragma unroll
  for (int nt = 0; nt < 4; ++nt) {
    bia0[nt] = bpack[(w << 6) + (nt << 4) + l16];
    bia1[nt] = bpack[G4_ + (w << 6) + (nt << 4) + l16];
  }

  float c0r[8], c1r[8];
#pragma unroll
  for (int e = 0; e < 8; ++e) { c0r[e] = 0.f; c1r[e] = 0.f; }
#pragma unroll
  for (int e = 0; e < 8; ++e) {
    A0[r_act][N_ + c_act + e] = (_Float16)0.f;  // h0 = 0
    A1[r_act][N_ + c_act + e] = (_Float16)0.f;  // h1 = 0
  }
  __syncthreads();

  const size_t browbase = (size_t)(nb * RPB_ + r_act) * T_;

  for (int t = 0; t < T_; ++t) {
    {  // stage xb = X_tilde*scale+shift into A0[:,0:128]
      const float* xrow = xt + (browbase + t) * N_ + c_act;
      const float* sc = scale + t * N_ + c_act;
      const float* sh = shift + t * N_ + c_act;
#pragma unroll
      for (int e = 0; e < 8; ++e)
        A0[r_act][c_act + e] = (_Float16)fmaf(xrow[e], sc[e], sh[e]);
    }
    __syncthreads();

    GEMM_LAYER(A0, 0, bia0)
    __syncthreads();

    {  // act0: update c0, h0n -> A0 high half (next step) + A1 low half (layer 1)
#pragma unroll
      for (int e = 0; e < 8; ++e) {
        int c = c_act + e;
        float ig = G[0][r_act][c];
        float fg = G[1][r_act][c];
        float gg = G[2][r_act][c];
        float og = G[3][r_act][c];
        float cn = sigm_(fg) * c0r[e] + sigm_(ig) * tanh_(gg);
        c0r[e] = cn;
        float hn = sigm_(og) * tanh_(cn);
        _Float16 hh = (_Float16)hn;
        A0[r_act][N_ + c] = hh;
        A1[r_act][c] = hh;
      }
    }
    __syncthreads();

    GEMM_LAYER(A1, G4_, bia1)
    __syncthreads();

    {  // act1: update c1, h1n -> A1 high half + output X_encoded
      float* orow = out1 + (browbase + t) * H_ + c_act;
#pragma unroll
      for (int e = 0; e < 8; ++e) {
        int c = c_act + e;
        float ig = G[0][r_act][c];
        float fg = G[1][r_act][c];
        float gg = G[2][r_act][c];
        float og = G[3][r_act][c];
        float cn = sigm_(fg) * c1r[e] + sigm_(ig) * tanh_(gg);
        c1r[e] = cn;
        float hn = sigm_(og) * tanh_(cn);
        A1[r_act][N_ + c] = (_Float16)hn;
        orow[e] = hn;
      }
    }
    __syncthreads();
  }
}

extern "C" void kernel_launch(void* const* d_in, const int* in_sizes, int n_in,
                              void* d_out, int out_size, void* d_ws, size_t ws_size,
                              hipStream_t stream) {
  const float* X = (const float*)d_in[0];
  const float* attnw = (const float*)d_in[1];
  const float* attnb = (const float*)d_in[2];
  const float* gamma = (const float*)d_in[3];
  const float* beta = (const float*)d_in[4];
  const float* Wih0 = (const float*)d_in[5];
  const float* Whh0 = (const float*)d_in[6];
  const float* bih0 = (const float*)d_in[7];
  const float* bhh0 = (const float*)d_in[8];
  const float* Wih1 = (const float*)d_in[9];
  const float* Whh1 = (const float*)d_in[10];
  const float* bih1 = (const float*)d_in[11];
  const float* bhh1 = (const float*)d_in[12];

  float* out0 = (float*)d_out;                    // X_tilde
  float* out1 = out0 + (size_t)B_ * T_ * N_;      // X_encoded

  float* ws = (float*)d_ws;
  float* alpha = ws;                              // B*N
  float* sumb = alpha + (size_t)B_ * N_;          // T*N
  float* sqb = sumb + T_ * N_;
  float* scale = sqb + T_ * N_;
  float* shift = scale + T_ * N_;
  float* bpack = shift + T_ * N_;                 // 2*512
  _Float16* Wpack = (_Float16*)(bpack + 2 * G4_); // 2*512*256 f16 (16B-aligned)

  k0_prep<<<1024, 256, 0, stream>>>(Wih0, Whh0, bih0, bhh0, Wih1, Whh1, bih1, bhh1,
                                    Wpack, bpack, sumb, sqb);
  k1_alpha<<<B_, 128, 0, stream>>>(X, attnw, attnb, alpha);
  k2_xtilde<<<dim3(T_, 16), 256, 0, stream>>>(X, alpha, out0, sumb, sqb);
  k3_finalize<<<64, 256, 0, stream>>>(sumb, sqb, gamma, beta, scale, shift);
  k4_recur<<<NB_, 512, 0, stream>>>(out0, Wpack, bpack, scale, shift, out1);
}